// Round 6
// baseline (75.832 us; speedup 1.0000x reference)
//
#include <hip/hip_runtime.h>
#include <stdint.h>

typedef float f32x4 __attribute__((ext_vector_type(4)));
typedef uint32_t u32x4 __attribute__((ext_vector_type(4)));
typedef short s16x8 __attribute__((ext_vector_type(8)));

#define BB   8
#define NN   2048
#define FIN  128
#define FOUT 64

__device__ __forceinline__ uint32_t cvt_pk_bf16(float lo, float hi) {
  uint32_t r;
  asm("v_cvt_pk_bf16_f32 %0, %1, %2" : "=v"(r) : "v"(lo), "v"(hi));
  return r;
}

__device__ __forceinline__ s16x8 mk_s16x8(uint32_t a, uint32_t b, uint32_t c, uint32_t d) {
  union { uint32_t u[4]; s16x8 v; } x;
  x.u[0] = a; x.u[1] = b; x.u[2] = c; x.u[3] = d;
  return x.v;
}

// ---------------------------------------------------------------------------
// Kernel 1: VERBATIM R1 (known-good). hidden = h @ W  (bf16 MFMA, f32 accum)
// grid: 256 blocks x 256 thr; each wave does 16 rows, block does 64 rows.
// ---------------------------------------------------------------------------
__global__ void k1_hidden(const float* __restrict__ h, const float* __restrict__ W,
                          const float* __restrict__ attw, ushort* __restrict__ hidT,
                          float* __restrict__ s1, float* __restrict__ s2) {
  __shared__ ushort wlds[FOUT * 136];   // W transposed, bf16, pitch 136 shorts
  const int tid = threadIdx.x;

  for (int idx = tid; idx < FIN * FOUT; idx += 256) {
    int k = idx >> 6, c = idx & 63;     // W row-major [k][c]
    wlds[c * 136 + k] = (ushort)(cvt_pk_bf16(W[idx], 0.f) & 0xffffu);
  }
  __syncthreads();

  const int lane = tid & 63, wid = tid >> 6;
  const int q = lane & 15, g = lane >> 4;
  const int wrow0 = blockIdx.x * 64 + wid * 16;
  const int b  = wrow0 >> 11;
  const int n0 = wrow0 & (NN - 1);

  const float* hrow = h + (size_t)(wrow0 + q) * FIN + 8 * g;

  f32x4 acc[4];
  #pragma unroll
  for (int nt = 0; nt < 4; ++nt) acc[nt] = {0.f, 0.f, 0.f, 0.f};

  #pragma unroll
  for (int kk = 0; kk < 4; ++kk) {
    f32x4 h0 = *(const f32x4*)(hrow + 32 * kk);
    f32x4 h1 = *(const f32x4*)(hrow + 32 * kk + 4);
    s16x8 A = mk_s16x8(cvt_pk_bf16(h0[0], h0[1]), cvt_pk_bf16(h0[2], h0[3]),
                       cvt_pk_bf16(h1[0], h1[1]), cvt_pk_bf16(h1[2], h1[3]));
    #pragma unroll
    for (int nt = 0; nt < 4; ++nt) {
      s16x8 Bf = *(const s16x8*)(&wlds[(nt * 16 + q) * 136 + 32 * kk + 8 * g]);
      acc[nt] = __builtin_amdgcn_mfma_f32_16x16x32_bf16(A, Bf, acc[nt], 0, 0, 0);
    }
  }

  // s1/s2: dot(hidden_row, a1/a2).  D layout: lane holds rows 4g+r, col q (per ntile).
  float a1v[4], a2v[4];
  #pragma unroll
  for (int nt = 0; nt < 4; ++nt) {
    a1v[nt] = attw[nt * 16 + q];
    a2v[nt] = attw[64 + nt * 16 + q];
  }
  float p1[4], p2[4];
  #pragma unroll
  for (int r = 0; r < 4; ++r) {
    float v1 = 0.f, v2 = 0.f;
    #pragma unroll
    for (int nt = 0; nt < 4; ++nt) { v1 += acc[nt][r] * a1v[nt]; v2 += acc[nt][r] * a2v[nt]; }
    #pragma unroll
    for (int m = 1; m < 16; m <<= 1) { v1 += __shfl_xor(v1, m, 64); v2 += __shfl_xor(v2, m, 64); }
    p1[r] = v1; p2[r] = v2;
  }
  if (q < 4) {
    int gr = wrow0 + 4 * g + q;
    float v1 = (q == 0) ? p1[0] : (q == 1) ? p1[1] : (q == 2) ? p1[2] : p1[3];
    float v2 = (q == 0) ? p2[0] : (q == 1) ? p2[1] : (q == 2) ? p2[2] : p2[3];
    s1[gr] = v1; s2[gr] = v2;
  }

  // hidT store: rows n0+4g..+3 (r packed), f = nt*16+q
  #pragma unroll
  for (int nt = 0; nt < 4; ++nt) {
    uint32_t lo = cvt_pk_bf16(acc[nt][0], acc[nt][1]);
    uint32_t hi = cvt_pk_bf16(acc[nt][2], acc[nt][3]);
    *(uint2*)(hidT + ((size_t)b * FOUT + nt * 16 + q) * NN + n0 + 4 * g) = make_uint2(lo, hi);
  }
}

// ---------------------------------------------------------------------------
// Kernel 2: masked softmax + PV.  Slim pipeline: adj = depth-3 register ring
// (the only HBM-latency stream); hidT (L2-hot) and s2l (LDS) just-in-time.
// No launch_bounds: allocator must not spill.  R1/R5 numerics (__expf, plain
// value semantics; nontemporal is a cache hint only).
// ---------------------------------------------------------------------------
__global__ void k2_attn(
    const float* __restrict__ adj, const ushort* __restrict__ hidT,
    const float* __restrict__ s1, const float* __restrict__ s2,
    float* __restrict__ out) {
  __shared__ float s2l[NN];
  __shared__ float part[4][16][64];
  __shared__ float partl[4][16];

  const int tid = threadIdx.x;
  const int bid = blockIdx.x;
  const int b  = bid >> 7;
  const int i0 = (bid & 127) << 4;

  {
    const f32x4* src = (const f32x4*)(s2 + b * NN);
    f32x4* dst = (f32x4*)s2l;
    for (int idx = tid; idx < NN / 4; idx += 256) dst[idx] = src[idx];
  }
  __syncthreads();

  const int lane = tid & 63, wid = tid >> 6;
  const int q = lane & 15, g = lane >> 4;
  const float s1r = s1[b * NN + i0 + q];

  const float*  adjrow = adj + (size_t)(b * NN + i0 + q) * NN;
  const ushort* hq0 = hidT + ((size_t)b * FOUT + q +  0) * NN;
  const ushort* hq1 = hidT + ((size_t)b * FOUT + q + 16) * NN;
  const ushort* hq2 = hidT + ((size_t)b * FOUT + q + 32) * NN;
  const ushort* hq3 = hidT + ((size_t)b * FOUT + q + 48) * NN;

  f32x4 acc0 = {0,0,0,0}, acc1 = {0,0,0,0}, acc2 = {0,0,0,0}, acc3 = {0,0,0,0};
  float lsum = 0.f;

  const int jbase = wid * 512 + 8 * g;

  // depth-3 adj prefetch ring (8 VGPR/slot, 24 total)
  f32x4 ra0[3], ra1[3];
  #pragma unroll
  for (int s = 0; s < 3; ++s) {
    ra0[s] = __builtin_nontemporal_load((const f32x4*)(adjrow + jbase + 32 * s));
    ra1[s] = __builtin_nontemporal_load((const f32x4*)(adjrow + jbase + 32 * s + 4));
  }

  #pragma unroll
  for (int s = 0; s < 16; ++s) {
    const int slot = s % 3;           // static after full unroll
    f32x4 a0 = ra0[slot], a1 = ra1[slot];
    if (s + 3 < 16) {
      const int jn = jbase + 32 * (s + 3);
      ra0[slot] = __builtin_nontemporal_load((const f32x4*)(adjrow + jn));
      ra1[slot] = __builtin_nontemporal_load((const f32x4*)(adjrow + jn + 4));
    }

    const int j0 = jbase + 32 * s;
    u32x4 cb0 = *(const u32x4*)(hq0 + j0);
    u32x4 cb1 = *(const u32x4*)(hq1 + j0);
    u32x4 cb2 = *(const u32x4*)(hq2 + j0);
    u32x4 cb3 = *(const u32x4*)(hq3 + j0);
    f32x4 ct0 = *(const f32x4*)(s2l + j0);
    f32x4 ct1 = *(const f32x4*)(s2l + j0 + 4);

    // p = adj * exp(leakyrelu(s1+s2));  adj is exactly 0 or 1
    float e0 = s1r + ct0[0], e1 = s1r + ct0[1], e2 = s1r + ct0[2], e3 = s1r + ct0[3];
    float e4 = s1r + ct1[0], e5 = s1r + ct1[1], e6 = s1r + ct1[2], e7 = s1r + ct1[3];
    float p0 = a0[0] * __expf(fmaxf(e0, 0.2f * e0));
    float p1 = a0[1] * __expf(fmaxf(e1, 0.2f * e1));
    float p2 = a0[2] * __expf(fmaxf(e2, 0.2f * e2));
    float p3 = a0[3] * __expf(fmaxf(e3, 0.2f * e3));
    float p4 = a1[0] * __expf(fmaxf(e4, 0.2f * e4));
    float p5 = a1[1] * __expf(fmaxf(e5, 0.2f * e5));
    float p6 = a1[2] * __expf(fmaxf(e6, 0.2f * e6));
    float p7 = a1[3] * __expf(fmaxf(e7, 0.2f * e7));
    lsum += ((p0 + p1) + (p2 + p3)) + ((p4 + p5) + (p6 + p7));

    s16x8 A = mk_s16x8(cvt_pk_bf16(p0, p1), cvt_pk_bf16(p2, p3),
                       cvt_pk_bf16(p4, p5), cvt_pk_bf16(p6, p7));
    union { u32x4 u; s16x8 v; } w0, w1, w2, w3;
    w0.u = cb0; w1.u = cb1; w2.u = cb2; w3.u = cb3;
    acc0 = __builtin_amdgcn_mfma_f32_16x16x32_bf16(A, w0.v, acc0, 0, 0, 0);
    acc1 = __builtin_amdgcn_mfma_f32_16x16x32_bf16(A, w1.v, acc1, 0, 0, 0);
    acc2 = __builtin_amdgcn_mfma_f32_16x16x32_bf16(A, w2.v, acc2, 0, 0, 0);
    acc3 = __builtin_amdgcn_mfma_f32_16x16x32_bf16(A, w3.v, acc3, 0, 0, 0);
  }

  // reduce row-sums over the 4 g-groups, stash per-wave partials
  lsum += __shfl_xor(lsum, 16, 64);
  lsum += __shfl_xor(lsum, 32, 64);
  if (lane < 16) partl[wid][lane] = lsum;

  #pragma unroll
  for (int r = 0; r < 4; ++r) {
    part[wid][4 * g + r][ 0 + q] = acc0[r];
    part[wid][4 * g + r][16 + q] = acc1[r];
    part[wid][4 * g + r][32 + q] = acc2[r];
    part[wid][4 * g + r][48 + q] = acc3[r];
  }
  __syncthreads();

  #pragma unroll
  for (int q4 = 0; q4 < 4; ++q4) {
    int idx = tid + 256 * q4;
    int row = idx >> 6, col = idx & 63;
    float v  = (part[0][row][col] + part[1][row][col]) +
               (part[2][row][col] + part[3][row][col]);
    float li = (partl[0][row] + partl[1][row]) + (partl[2][row] + partl[3][row]);
    float hp = v / li;
    out[(size_t)(b * NN + i0 + row) * 64 + col] = (hp > 0.f) ? hp : expm1f(hp);
  }
}

extern "C" void kernel_launch(void* const* d_in, const int* in_sizes, int n_in,
                              void* d_out, int out_size, void* d_ws, size_t ws_size,
                              hipStream_t stream) {
  const float* h    = (const float*)d_in[0];
  const float* adj  = (const float*)d_in[1];
  const float* W    = (const float*)d_in[2];
  const float* attw = (const float*)d_in[3];
  float* out = (float*)d_out;

  char* ws = (char*)d_ws;
  ushort* hidT = (ushort*)ws;                                   // 2 MB
  float*  s1   = (float*)(ws + (2u << 20));                     // 64 KB
  float*  s2   = (float*)(ws + (2u << 20) + (64u << 10));       // 64 KB

  hipLaunchKernelGGL(k1_hidden, dim3(256), dim3(256), 0, stream, h, W, attw, hidT, s1, s2);
  hipLaunchKernelGGL(k2_attn, dim3(BB * (NN / 16)), dim3(256), 0, stream, adj, hidT, s1, s2, out);
}

// Round 7
// 63.171 us; speedup vs baseline: 1.2004x; 1.2004x over previous
//
#include <hip/hip_runtime.h>
#include <stdint.h>

typedef float f32x4 __attribute__((ext_vector_type(4)));
typedef uint32_t u32x4 __attribute__((ext_vector_type(4)));
typedef short s16x8 __attribute__((ext_vector_type(8)));

#define BB   8
#define NN   2048
#define FIN  128
#define FOUT 64

__device__ __forceinline__ uint32_t cvt_pk_bf16(float lo, float hi) {
  uint32_t r;
  asm("v_cvt_pk_bf16_f32 %0, %1, %2" : "=v"(r) : "v"(lo), "v"(hi));
  return r;
}

__device__ __forceinline__ s16x8 mk_s16x8(uint32_t a, uint32_t b, uint32_t c, uint32_t d) {
  union { uint32_t u[4]; s16x8 v; } x;
  x.u[0] = a; x.u[1] = b; x.u[2] = c; x.u[3] = d;
  return x.v;
}

// ---------------------------------------------------------------------------
// Kernel 1: R1 body (known-good) + XCD swizzle so XCD x writes batch x's hidT.
// grid: 256 blocks x 256 thr; each wave does 16 rows, block does 64 rows.
// ---------------------------------------------------------------------------
__global__ void k1_hidden(const float* __restrict__ h, const float* __restrict__ W,
                          const float* __restrict__ attw, ushort* __restrict__ hidT,
                          float* __restrict__ s1, float* __restrict__ s2) {
  __shared__ ushort wlds[FOUT * 136];   // W transposed, bf16, pitch 136 shorts
  const int tid = threadIdx.x;

  for (int idx = tid; idx < FIN * FOUT; idx += 256) {
    int k = idx >> 6, c = idx & 63;     // W row-major [k][c]
    wlds[c * 136 + k] = (ushort)(cvt_pk_bf16(W[idx], 0.f) & 0xffffu);
  }
  __syncthreads();

  // XCD swizzle: 256 blocks, XCD = bid%8 (round-robin assumption, perf-only).
  // Give XCD x the contiguous chunk [x*32, x*32+32) -> batch x exactly.
  const int bid = ((blockIdx.x & 7) << 5) | (blockIdx.x >> 3);

  const int lane = tid & 63, wid = tid >> 6;
  const int q = lane & 15, g = lane >> 4;
  const int wrow0 = bid * 64 + wid * 16;
  const int b  = wrow0 >> 11;
  const int n0 = wrow0 & (NN - 1);

  const float* hrow = h + (size_t)(wrow0 + q) * FIN + 8 * g;

  f32x4 acc[4];
  #pragma unroll
  for (int nt = 0; nt < 4; ++nt) acc[nt] = {0.f, 0.f, 0.f, 0.f};

  #pragma unroll
  for (int kk = 0; kk < 4; ++kk) {
    f32x4 h0 = *(const f32x4*)(hrow + 32 * kk);
    f32x4 h1 = *(const f32x4*)(hrow + 32 * kk + 4);
    s16x8 A = mk_s16x8(cvt_pk_bf16(h0[0], h0[1]), cvt_pk_bf16(h0[2], h0[3]),
                       cvt_pk_bf16(h1[0], h1[1]), cvt_pk_bf16(h1[2], h1[3]));
    #pragma unroll
    for (int nt = 0; nt < 4; ++nt) {
      s16x8 Bf = *(const s16x8*)(&wlds[(nt * 16 + q) * 136 + 32 * kk + 8 * g]);
      acc[nt] = __builtin_amdgcn_mfma_f32_16x16x32_bf16(A, Bf, acc[nt], 0, 0, 0);
    }
  }

  // s1/s2: dot(hidden_row, a1/a2).  D layout: lane holds rows 4g+r, col q (per ntile).
  float a1v[4], a2v[4];
  #pragma unroll
  for (int nt = 0; nt < 4; ++nt) {
    a1v[nt] = attw[nt * 16 + q];
    a2v[nt] = attw[64 + nt * 16 + q];
  }
  float p1[4], p2[4];
  #pragma unroll
  for (int r = 0; r < 4; ++r) {
    float v1 = 0.f, v2 = 0.f;
    #pragma unroll
    for (int nt = 0; nt < 4; ++nt) { v1 += acc[nt][r] * a1v[nt]; v2 += acc[nt][r] * a2v[nt]; }
    #pragma unroll
    for (int m = 1; m < 16; m <<= 1) { v1 += __shfl_xor(v1, m, 64); v2 += __shfl_xor(v2, m, 64); }
    p1[r] = v1; p2[r] = v2;
  }
  if (q < 4) {
    int gr = wrow0 + 4 * g + q;
    float v1 = (q == 0) ? p1[0] : (q == 1) ? p1[1] : (q == 2) ? p1[2] : p1[3];
    float v2 = (q == 0) ? p2[0] : (q == 1) ? p2[1] : (q == 2) ? p2[2] : p2[3];
    s1[gr] = v1; s2[gr] = v2;
  }

  // hidT store: rows n0+4g..+3 (r packed), f = nt*16+q
  #pragma unroll
  for (int nt = 0; nt < 4; ++nt) {
    uint32_t lo = cvt_pk_bf16(acc[nt][0], acc[nt][1]);
    uint32_t hi = cvt_pk_bf16(acc[nt][2], acc[nt][3]);
    *(uint2*)(hidT + ((size_t)b * FOUT + nt * 16 + q) * NN + n0 + 4 * g) = make_uint2(lo, hi);
  }
}

// ---------------------------------------------------------------------------
// Kernel 2: R5 body (best: 63.3us) + XCD swizzle so XCD x reads batch x's
// hidT from its own L2.  2-deep pipeline, plain loads, __expf.
// ---------------------------------------------------------------------------
__global__ __launch_bounds__(256, 4) void k2_attn(
    const float* __restrict__ adj, const ushort* __restrict__ hidT,
    const float* __restrict__ s1, const float* __restrict__ s2,
    float* __restrict__ out) {
  __shared__ float s2l[NN];
  __shared__ float part[4][16][64];
  __shared__ float partl[4][16];

  const int tid = threadIdx.x;
  // XCD swizzle: 1024 blocks; XCD x -> contiguous [x*128, x*128+128) = batch x.
  const int bid = ((blockIdx.x & 7) << 7) | (blockIdx.x >> 3);
  const int b  = bid >> 7;
  const int i0 = (bid & 127) << 4;

  {
    const f32x4* src = (const f32x4*)(s2 + b * NN);
    f32x4* dst = (f32x4*)s2l;
    for (int idx = tid; idx < NN / 4; idx += 256) dst[idx] = src[idx];
  }
  __syncthreads();

  const int lane = tid & 63, wid = tid >> 6;
  const int q = lane & 15, g = lane >> 4;
  const float s1r = s1[b * NN + i0 + q];

  const float*  adjrow = adj + (size_t)(b * NN + i0 + q) * NN;
  const ushort* hq     = hidT + ((size_t)b * FOUT + q) * NN;

  f32x4 acc0 = {0,0,0,0}, acc1 = {0,0,0,0}, acc2 = {0,0,0,0}, acc3 = {0,0,0,0};
  float lsum = 0.f;

  const int jbase = wid * 512 + 8 * g;

  f32x4 ca0, ca1, ct0, ct1; u32x4 cb0, cb1, cb2, cb3;
  {
    const int j0 = jbase;
    ca0 = *(const f32x4*)(adjrow + j0);
    ca1 = *(const f32x4*)(adjrow + j0 + 4);
    ct0 = *(const f32x4*)(s2l + j0);
    ct1 = *(const f32x4*)(s2l + j0 + 4);
    cb0 = *(const u32x4*)(hq + (size_t)0 * 16 * NN + j0);
    cb1 = *(const u32x4*)(hq + (size_t)1 * 16 * NN + j0);
    cb2 = *(const u32x4*)(hq + (size_t)2 * 16 * NN + j0);
    cb3 = *(const u32x4*)(hq + (size_t)3 * 16 * NN + j0);
  }

  #pragma unroll
  for (int s = 0; s < 16; ++s) {
    f32x4 na0, na1, nt0, nt1; u32x4 nb0, nb1, nb2, nb3;
    if (s < 15) {
      const int j0 = jbase + 32 * (s + 1);
      na0 = *(const f32x4*)(adjrow + j0);
      na1 = *(const f32x4*)(adjrow + j0 + 4);
      nt0 = *(const f32x4*)(s2l + j0);
      nt1 = *(const f32x4*)(s2l + j0 + 4);
      nb0 = *(const u32x4*)(hq + (size_t)0 * 16 * NN + j0);
      nb1 = *(const u32x4*)(hq + (size_t)1 * 16 * NN + j0);
      nb2 = *(const u32x4*)(hq + (size_t)2 * 16 * NN + j0);
      nb3 = *(const u32x4*)(hq + (size_t)3 * 16 * NN + j0);
    }

    // p = adj * exp(leakyrelu(s1+s2));  adj is exactly 0 or 1
    float e0 = s1r + ct0[0], e1 = s1r + ct0[1], e2 = s1r + ct0[2], e3 = s1r + ct0[3];
    float e4 = s1r + ct1[0], e5 = s1r + ct1[1], e6 = s1r + ct1[2], e7 = s1r + ct1[3];
    float p0 = ca0[0] * __expf(fmaxf(e0, 0.2f * e0));
    float p1 = ca0[1] * __expf(fmaxf(e1, 0.2f * e1));
    float p2 = ca0[2] * __expf(fmaxf(e2, 0.2f * e2));
    float p3 = ca0[3] * __expf(fmaxf(e3, 0.2f * e3));
    float p4 = ca1[0] * __expf(fmaxf(e4, 0.2f * e4));
    float p5 = ca1[1] * __expf(fmaxf(e5, 0.2f * e5));
    float p6 = ca1[2] * __expf(fmaxf(e6, 0.2f * e6));
    float p7 = ca1[3] * __expf(fmaxf(e7, 0.2f * e7));
    lsum += ((p0 + p1) + (p2 + p3)) + ((p4 + p5) + (p6 + p7));

    s16x8 A = mk_s16x8(cvt_pk_bf16(p0, p1), cvt_pk_bf16(p2, p3),
                       cvt_pk_bf16(p4, p5), cvt_pk_bf16(p6, p7));
    union { u32x4 u; s16x8 v; } w0, w1, w2, w3;
    w0.u = cb0; w1.u = cb1; w2.u = cb2; w3.u = cb3;
    acc0 = __builtin_amdgcn_mfma_f32_16x16x32_bf16(A, w0.v, acc0, 0, 0, 0);
    acc1 = __builtin_amdgcn_mfma_f32_16x16x32_bf16(A, w1.v, acc1, 0, 0, 0);
    acc2 = __builtin_amdgcn_mfma_f32_16x16x32_bf16(A, w2.v, acc2, 0, 0, 0);
    acc3 = __builtin_amdgcn_mfma_f32_16x16x32_bf16(A, w3.v, acc3, 0, 0, 0);

    if (s < 15) {
      ca0 = na0; ca1 = na1; ct0 = nt0; ct1 = nt1;
      cb0 = nb0; cb1 = nb1; cb2 = nb2; cb3 = nb3;
    }
  }

  // reduce row-sums over the 4 g-groups, stash per-wave partials
  lsum += __shfl_xor(lsum, 16, 64);
  lsum += __shfl_xor(lsum, 32, 64);
  if (lane < 16) partl[wid][lane] = lsum;

  #pragma unroll
  for (int r = 0; r < 4; ++r) {
    part[wid][4 * g + r][ 0 + q] = acc0[r];
    part[wid][4 * g + r][16 + q] = acc1[r];
    part[wid][4 * g + r][32 + q] = acc2[r];
    part[wid][4 * g + r][48 + q] = acc3[r];
  }
  __syncthreads();

  #pragma unroll
  for (int q4 = 0; q4 < 4; ++q4) {
    int idx = tid + 256 * q4;
    int row = idx >> 6, col = idx & 63;
    float v  = (part[0][row][col] + part[1][row][col]) +
               (part[2][row][col] + part[3][row][col]);
    float li = (partl[0][row] + partl[1][row]) + (partl[2][row] + partl[3][row]);
    float hp = v / li;
    out[(size_t)(b * NN + i0 + row) * 64 + col] = (hp > 0.f) ? hp : expm1f(hp);
  }
}

extern "C" void kernel_launch(void* const* d_in, const int* in_sizes, int n_in,
                              void* d_out, int out_size, void* d_ws, size_t ws_size,
                              hipStream_t stream) {
  const float* h    = (const float*)d_in[0];
  const float* adj  = (const float*)d_in[1];
  const float* W    = (const float*)d_in[2];
  const float* attw = (const float*)d_in[3];
  float* out = (float*)d_out;

  char* ws = (char*)d_ws;
  ushort* hidT = (ushort*)ws;                                   // 2 MB
  float*  s1   = (float*)(ws + (2u << 20));                     // 64 KB
  float*  s2   = (float*)(ws + (2u << 20) + (64u << 10));       // 64 KB

  hipLaunchKernelGGL(k1_hidden, dim3(256), dim3(256), 0, stream, h, W, attw, hidT, s1, s2);
  hipLaunchKernelGGL(k2_attn, dim3(BB * (NN / 16)), dim3(256), 0, stream, adj, hidT, s1, s2, out);
}